// Round 8
// baseline (661.908 us; speedup 1.0000x reference)
//
#include <hip/hip_runtime.h>
#include <math.h>

#define Bq    128
#define Dq    128
#define Hq    50
#define NEGq  4
#define Lq    30
#define Sq    55      // H + 1 + NEG
#define NPGq  80
#define Nq    10240   // B * NPG
#define Eq    163840  // N * 16
#define NEWSq 7040    // B * S
#define BEq   28160   // NEWS * 4
#define WVOCq 50000
#define NEG1q 5

__device__ __forceinline__ float leaky_f(float x) { return x > 0.f ? x : 0.2f * x; }

// ---------------------------------------------------------------- matmul core (R6-proven)
#define MMROWS 32

#define MM4(RR, CC, WC) \
    f[RR][CC] = fmaf(a.x, w0.WC, f[RR][CC]); \
    f[RR][CC] = fmaf(a.y, w1.WC, f[RR][CC]); \
    f[RR][CC] = fmaf(a.z, w2.WC, f[RR][CC]); \
    f[RR][CC] = fmaf(a.w, w3.WC, f[RR][CC]);

__device__ __forceinline__ void mm_compute(float* sW, float (*sA)[32],
        const float* __restrict__ A, const float* __restrict__ W,
        int M, int r0, int amap, double acc[4][4]) {
    int tid = threadIdx.x;
    int tx = tid & 31;
    int ty = tid >> 5;
    int j0 = tx * 4;
#pragma unroll
    for (int rr = 0; rr < 4; ++rr)
#pragma unroll
        for (int cc = 0; cc < 4; ++cc) acc[rr][cc] = 0.0;

    for (int ks = 0; ks < 4; ++ks) {
        __syncthreads();
        const float4* W4 = (const float4*)(W + ks * 32 * 128);
        float4* sW4 = (float4*)sW;
#pragma unroll
        for (int i = tid; i < 32 * 32; i += 256) sW4[i] = W4[i];
        {
            int r = tid >> 3, c4 = tid & 7;
            int gr = r0 + r;
            float4 v = make_float4(0.f, 0.f, 0.f, 0.f);
            if (gr < M) {
                long pr = amap ? (long)((gr / Hq) * Sq + gr % Hq) : (long)gr;
                v = *(const float4*)(A + pr * 128 + ks * 32 + c4 * 4);
            }
            *(float4*)&sA[r][c4 * 4] = v;
        }
        __syncthreads();
        float f[4][4];
#pragma unroll
        for (int rr = 0; rr < 4; ++rr)
#pragma unroll
            for (int cc = 0; cc < 4; ++cc) f[rr][cc] = 0.f;
#pragma unroll
        for (int k = 0; k < 32; k += 4) {
            float4 w0 = *(const float4*)&sW[(k + 0) * 128 + j0];
            float4 w1 = *(const float4*)&sW[(k + 1) * 128 + j0];
            float4 w2 = *(const float4*)&sW[(k + 2) * 128 + j0];
            float4 w3 = *(const float4*)&sW[(k + 3) * 128 + j0];
#pragma unroll
            for (int rr = 0; rr < 4; ++rr) {
                float4 a = *(const float4*)&sA[ty * 4 + rr][k];
                MM4(rr, 0, x) MM4(rr, 1, y) MM4(rr, 2, z) MM4(rr, 3, w)
            }
        }
#pragma unroll
        for (int rr = 0; rr < 4; ++rr)
#pragma unroll
            for (int cc = 0; cc < 4; ++cc) acc[rr][cc] += (double)f[rr][cc];
    }
}

// tanh-dot epilogue body
__device__ __forceinline__ void mm_tanh_body(float* sW, float (*sA)[32],
        const float* __restrict__ A, const float* __restrict__ W, int M, int r0,
        const float* __restrict__ q0, const float* __restrict__ q1, float* __restrict__ o0) {
    double acc[4][4];
    mm_compute(sW, sA, A, W, M, r0, 0, acc);
    int tid = threadIdx.x, tx = tid & 31, ty = tid >> 5;
    int j0 = tx * 4;
    float q0c[4], q1c[4];
#pragma unroll
    for (int cc = 0; cc < 4; ++cc) { q0c[cc] = q0[j0 + cc]; q1c[cc] = q1[j0 + cc]; }
#pragma unroll
    for (int rr = 0; rr < 4; ++rr) {
        int r = r0 + ty * 4 + rr;
        double s = 0.0;
#pragma unroll
        for (int cc = 0; cc < 4; ++cc) {
            float t = (float)acc[rr][cc] + q0c[cc];
            s += (double)tanhf(t) * (double)q1c[cc];
        }
        for (int o = 16; o > 0; o >>= 1) s += __shfl_xor(s, o);
        if ((tid & 31) == 0 && r < M) o0[r] = (float)s;
    }
}

__global__ __launch_bounds__(256) void k_mm_tanh(const float* __restrict__ A,
        const float* __restrict__ W, int M,
        const float* __restrict__ q0, const float* __restrict__ q1, float* __restrict__ o0) {
    __shared__ float sW[32 * 128];
    __shared__ float sA[MMROWS][32];
    mm_tanh_body(sW, sA, A, W, M, blockIdx.x * MMROWS, q0, q1, o0);
}

// ---- generic job-table matmul
struct MMJob {
    const float* A; const float* W; float* C;
    const float* q0; const float* q1;
    float* o0; float* o1;
    int M; int blk_end; int amap;
};
struct MMJobs { MMJob j[4]; };

__device__ __forceinline__ void mm_job_body(float* sW, float (*sA)[32], MMJob J, int r0) {
    double acc[4][4];
    mm_compute(sW, sA, J.A, J.W, J.M, r0, J.amap, acc);
    int tid = threadIdx.x, tx = tid & 31, ty = tid >> 5;
    int j0 = tx * 4;
    if (J.C) {
#pragma unroll
        for (int rr = 0; rr < 4; ++rr) {
            int r = r0 + ty * 4 + rr;
            if (r < J.M) {
                float4 o = make_float4((float)acc[rr][0], (float)acc[rr][1],
                                       (float)acc[rr][2], (float)acc[rr][3]);
                *(float4*)&J.C[(long)r * 128 + j0] = o;
            }
        }
    }
    if (J.o0) {
        float q0c[4], q1c[4];
        bool two = (J.q1 != nullptr);
#pragma unroll
        for (int cc = 0; cc < 4; ++cc) {
            q0c[cc] = J.q0[j0 + cc];
            q1c[cc] = two ? J.q1[j0 + cc] : 0.f;
        }
#pragma unroll
        for (int rr = 0; rr < 4; ++rr) {
            int r = r0 + ty * 4 + rr;
            double d0 = 0.0, d1 = 0.0;
#pragma unroll
            for (int cc = 0; cc < 4; ++cc) {
                double c = (double)(float)acc[rr][cc];
                d0 += c * (double)q0c[cc];
                d1 += c * (double)q1c[cc];
            }
            for (int o = 16; o > 0; o >>= 1) {
                d0 += __shfl_xor(d0, o);
                if (two) d1 += __shfl_xor(d1, o);
            }
            if ((tid & 31) == 0 && r < J.M) {
                J.o0[r] = (float)d0;
                if (two) J.o1[r] = (float)d1;
            }
        }
    }
}

__global__ __launch_bounds__(256) void k_mm_jobs(MMJobs js) {
    __shared__ float sW[32 * 128];
    __shared__ float sA[MMROWS][32];
    int bid = blockIdx.x;
    int ji = 0, blk0 = 0;
#pragma unroll
    for (int t = 0; t < 3; ++t)
        if (bid >= js.j[t].blk_end) { ji = t + 1; blk0 = js.j[t].blk_end; }
    mm_job_body(sW, sA, js.j[ji], (bid - blk0) * MMROWS);
}

// ---------------------------------------------------------------- misc1: CSR count || embed || word-score || wdvec prep
__global__ __launch_bounds__(256) void k_misc1(
        const int* __restrict__ ei_dst, const int* __restrict__ bi_node, const int* __restrict__ bi_news,
        int* __restrict__ cg, int* __restrict__ cbn, int* __restrict__ cbw,
        const int* __restrict__ nodes, const float* __restrict__ ent, float* __restrict__ v0,
        const float* __restrict__ wemb, const float* __restrict__ teW,
        const float* __restrict__ teb, const float* __restrict__ tev, float* __restrict__ wscore,
        const float* __restrict__ Wd1, const float* __restrict__ ad1, float* __restrict__ wdvec1,
        const float* __restrict__ Wd2, const float* __restrict__ ad2, float* __restrict__ wdvec2,
        int n_count, int n_embed, int n_ws) {
    __shared__ float sW[32 * 128];
    __shared__ float sA[MMROWS][32];
    int blk = blockIdx.x;
    if (blk < n_count) {
        int e = blk * 256 + threadIdx.x;
        if (e < Eq) atomicAdd(&cg[ei_dst[e]], 1);
        else if (e < Eq + BEq) atomicAdd(&cbn[bi_node[e - Eq]], 1);
        else if (e < Eq + 2 * BEq) atomicAdd(&cbw[bi_news[e - Eq - BEq]], 1);
    } else if (blk < n_count + n_embed) {
        int i = (blk - n_count) * 256 + threadIdx.x;
        if (i < Nq * 32) {
            int r = i >> 5, d = i & 31;
            ((float4*)v0)[i] = ((const float4*)(ent + (long)nodes[r] * 128))[d];
        }
    } else if (blk < n_count + n_embed + n_ws) {
        int r0 = (blk - n_count - n_embed) * MMROWS;
        mm_tanh_body(sW, sA, wemb, teW, WVOCq, r0, teb, tev, wscore);
    } else {
        // wdvec[k] = sum_j Wd[k][j] * ad[j]  (f64)
        int t = threadIdx.x;
        const float* Wd = (t < 128) ? Wd1 : Wd2;
        const float* ad = (t < 128) ? ad1 : ad2;
        float* ov = (t < 128) ? wdvec1 : wdvec2;
        int kk = t & 127;
        double s = 0.0;
        for (int j = 0; j < 128; ++j)
            s += (double)Wd[kk * 128 + j] * (double)ad[j];
        ov[kk] = (float)s;
    }
}

// ---------------------------------------------------------------- scan (3 blocks)
__global__ __launch_bounds__(1024) void k_scan3(
        const int* __restrict__ cg, const int* __restrict__ cbn, const int* __restrict__ cbw,
        int* __restrict__ og, int* __restrict__ obn, int* __restrict__ obw,
        int* __restrict__ curg, int* __restrict__ curbn, int* __restrict__ curbw) {
    __shared__ int part[1024];
    const int* cnt; int* off; int* cur; int n;
    if (blockIdx.x == 0)      { cnt = cg;  off = og;  cur = curg;  n = Nq; }
    else if (blockIdx.x == 1) { cnt = cbn; off = obn; cur = curbn; n = Nq; }
    else                      { cnt = cbw; off = obw; cur = curbw; n = NEWSq; }
    int tid = threadIdx.x;
    int chunk = (n + 1023) >> 10;
    int s0 = tid * chunk;
    int s1 = s0 + chunk; if (s1 > n) s1 = n;
    int s = 0;
    for (int i = s0; i < s1; ++i) s += cnt[i];
    part[tid] = s;
    __syncthreads();
    for (int d = 1; d < 1024; d <<= 1) {
        int v = (tid >= d) ? part[tid - d] : 0;
        __syncthreads();
        part[tid] += v;
        __syncthreads();
    }
    int base = (tid > 0) ? part[tid - 1] : 0;
    for (int i = s0; i < s1; ++i) { off[i] = base; cur[i] = base; base += cnt[i]; }
    if (tid == 0) off[n] = part[1023];
}

// ---------------------------------------------------------------- misc2: CSR scatter || title-pool (2/block)
__global__ __launch_bounds__(256) void k_misc2(
        const int* __restrict__ ei_src, const int* __restrict__ ei_dst,
        const int* __restrict__ bi_news, const int* __restrict__ bi_node,
        int* __restrict__ curg, int* __restrict__ curbn, int* __restrict__ curbw,
        int* __restrict__ g_out, int* __restrict__ bn_out, int* __restrict__ bw_out,
        const int* __restrict__ title_tok, const float* __restrict__ wscore,
        const float* __restrict__ wemb,
        const int* __restrict__ hist_seqs, const int* __restrict__ hist_lens,
        const int* __restrict__ pos_seq, const int* __restrict__ pos_len,
        const int* __restrict__ neg_seqs, const int* __restrict__ neg_lens,
        float* __restrict__ UTraw, float* __restrict__ news1, int n_scatter) {
    __shared__ int tok[2][Lq];
    __shared__ float wgt[2][Lq];
    __shared__ double sden[2];
    int blk = blockIdx.x;
    if (blk < n_scatter) {
        int e = blk * 256 + threadIdx.x;
        if (e < Eq) {
            int slot = atomicAdd(&curg[ei_dst[e]], 1);
            g_out[slot] = ei_src[e];
        } else if (e < Eq + BEq) {
            int i = e - Eq;
            int slot = atomicAdd(&curbn[bi_node[i]], 1);
            bn_out[slot] = bi_news[i];
        } else if (e < Eq + 2 * BEq) {
            int i = e - Eq - BEq;
            int slot = atomicAdd(&curbw[bi_news[i]], 1);
            bw_out[slot] = bi_node[i];
        }
        return;
    }
    int half = threadIdx.x >> 7;
    int tid = threadIdx.x & 127;
    int t = (blk - n_scatter) * 2 + half;
    int b = t / Sq, s = t % Sq;
    int nid, len; float* dst;
    if (s < Hq)       { nid = hist_seqs[b * Hq + s]; len = hist_lens[b * Hq + s]; dst = UTraw + (long)(b * Hq + s) * 128; }
    else if (s == Hq) { nid = pos_seq[b];            len = pos_len[b];            dst = news1 + (long)t * 128; }
    else { int g = s - Hq - 1; nid = neg_seqs[b * NEGq + g]; len = neg_lens[b * NEGq + g]; dst = news1 + (long)t * 128; }

    if (tid < Lq) tok[half][tid] = title_tok[(long)nid * Lq + tid];
    __syncthreads();
    if (tid < 64) {
        float sc = (tid < len) ? wscore[tok[half][tid]] : -1e30f;
        float mx = sc;
        for (int o = 32; o > 0; o >>= 1) mx = fmaxf(mx, __shfl_xor(mx, o));
        float e = (tid < len) ? (float)exp((double)(sc - mx)) : 0.f;
        if (tid < Lq) wgt[half][tid] = e;
        double ds = (double)e;
        for (int o = 32; o > 0; o >>= 1) ds += __shfl_xor(ds, o);
        if (tid == 0) sden[half] = ds;
    }
    __syncthreads();
    double den = sden[half];
    double acc = 0.0;
    for (int l = 0; l < len; ++l)
        acc += (double)wgt[half][l] * (double)wemb[(long)tok[half][l] * 128 + tid];
    dst[tid] = (float)(acc / den);
}

// ---------------------------------------------------------------- edge aggregation: wave per segment
#define WMAXK 128
struct EASet {
    const int* off; const int* srcs;
    const float* es; const float* ed;     // ed: per-seg scalar array, OR
    const float* edvec;                   // edvec: inline dot Xdst row . edvec (cross layers)
    const float* Hsrc; const float* Xdst;
    float* Out; int nseg; int mode;
};

__device__ __forceinline__ void ea_body(EASet S, int n, int wv, int lane,
        int (*sSrc)[WMAXK], float (*sE)[WMAXK],
        const float* __restrict__ gW, const float* __restrict__ gb, float* __restrict__ gout,
        bool doGate) {
    int s0 = S.off[n], k = S.off[n + 1] - s0;
    int d0 = lane * 2;
    float o0, o1;
    float2 xres = make_float2(0.f, 0.f);
    if (S.mode) xres = *(const float2*)&S.Xdst[(long)n * 128 + d0];
    if (k == 0) {
        o0 = S.mode ? xres.x : 0.f;
        o1 = S.mode ? xres.y : 0.f;
    } else {
        float edn;
        if (S.edvec) {
            double pp = (double)xres.x * (double)S.edvec[d0] + (double)xres.y * (double)S.edvec[d0 + 1];
            for (int o = 32; o > 0; o >>= 1) pp += __shfl_xor(pp, o);
            edn = (float)pp;
        } else {
            edn = S.ed[n];
        }
        float mloc = -1e30f;
        for (int j = lane; j < k; j += 64) {
            int sidx = S.srcs[s0 + j];
            float e = leaky_f(S.es[sidx] + edn);
            if (j < WMAXK) { sSrc[wv][j] = sidx; sE[wv][j] = e; }
            mloc = fmaxf(mloc, e);
        }
        for (int o = 32; o > 0; o >>= 1) mloc = fmaxf(mloc, __shfl_xor(mloc, o));
        float m = mloc;
        double dloc = 0.0;
        for (int j = lane; j < k; j += 64) {
            float e = (j < WMAXK) ? sE[wv][j] : leaky_f(S.es[S.srcs[s0 + j]] + edn);
            float ex = (float)exp((double)(e - m));
            if (j < WMAXK) sE[wv][j] = ex;
            dloc += (double)ex;
        }
        for (int o = 32; o > 0; o >>= 1) dloc += __shfl_xor(dloc, o);
        double den = dloc + 1e-16;
        for (int j = lane; j < k && j < WMAXK; j += 64)
            sE[wv][j] = (float)((double)sE[wv][j] / den);
        double a0 = 0.0, a1 = 0.0;
        for (int j = 0; j < k; ++j) {
            float alpha; int sidx;
            if (j < WMAXK) { alpha = sE[wv][j]; sidx = sSrc[wv][j]; }
            else {
                sidx = S.srcs[s0 + j];
                float e = leaky_f(S.es[sidx] + edn);
                float ex = (float)exp((double)(e - m));
                alpha = (float)((double)ex / den);
            }
            float2 h = *(const float2*)&S.Hsrc[(long)sidx * 128 + d0];
            a0 += (double)alpha * (double)h.x;
            a1 += (double)alpha * (double)h.y;
        }
        float v0f = (float)a0, v1f = (float)a1;
        o0 = (v0f > 0.f) ? v0f : (float)expm1((double)v0f);
        o1 = (v1f > 0.f) ? v1f : (float)expm1((double)v1f);
        if (S.mode) { o0 += xres.x; o1 += xres.y; }
    }
    *(float2*)&S.Out[(long)n * 128 + d0] = make_float2(o0, o1);
    if (doGate && gout) {
        double part = (double)o0 * (double)gW[d0] + (double)o1 * (double)gW[d0 + 1];
        for (int o = 32; o > 0; o >>= 1) part += __shfl_xor(part, o);
        if (lane == 0) gout[n] = (float)part + gb[0];
    }
}

__global__ __launch_bounds__(256) void k_edge_agg_w(EASet a, EASet b,
        const float* __restrict__ gW, const float* __restrict__ gb, float* __restrict__ gout) {
    __shared__ int   sSrc[4][WMAXK];
    __shared__ float sE[4][WMAXK];
    int wv = threadIdx.x >> 6, lane = threadIdx.x & 63;
    int g = blockIdx.x * 4 + wv;
    if (g >= a.nseg + b.nseg) return;
    bool isA = g < a.nseg;
    ea_body(isA ? a : b, isA ? g : g - a.nseg, wv, lane, sSrc, sE, gW, gb, gout, isA);
}

// ---- combined: one MM job (blocks [0,nMM)) || edge-agg (rest)
__global__ __launch_bounds__(256) void k_ea_mm(MMJob mj, int nMM, EASet a, EASet b) {
    __shared__ float sW[32 * 128];
    __shared__ float sA[MMROWS][32];
    __shared__ int   sSrc[4][WMAXK];
    __shared__ float sE[4][WMAXK];
    int blk = blockIdx.x;
    if (blk < nMM) {
        mm_job_body(sW, sA, mj, blk * MMROWS);
        return;
    }
    int wv = threadIdx.x >> 6, lane = threadIdx.x & 63;
    int g = (blk - nMM) * 4 + wv;
    if (g >= a.nseg + b.nseg) return;
    bool isA = g < a.nseg;
    ea_body(isA ? a : b, isA ? g : g - a.nseg, wv, lane, sSrc, sE, nullptr, nullptr, nullptr, false);
}

// ---------------------------------------------------------------- self-attention (flat-parallel)
__global__ __launch_bounds__(256) void k_self_attn(const float* __restrict__ Q, const float* __restrict__ K,
                                                   const float* __restrict__ V, float* __restrict__ Out,
                                                   int ob_stride, const float* __restrict__ tail_src) {
    __shared__ float sQ[Hq][129];
    __shared__ float sK[Hq][129];
    __shared__ float sV[Hq * 128];
    __shared__ float sEx[Hq][52];
    __shared__ double sInv[Hq];
    const double SQRTD = (double)11.3137085f;
    int b = blockIdx.x;
    int tid = threadIdx.x;
    const float* Qb = Q + (long)b * Hq * 128;
    const float* Kb = K + (long)b * Hq * 128;
    const float* Vb = V + (long)b * Hq * 128;
    for (int idx = tid; idx < Hq * 128; idx += 256) {
        int r = idx >> 7, i = idx & 127;
        sQ[r][i] = Qb[idx];
        sK[r][i] = Kb[idx];
        sV[idx] = Vb[idx];
    }
    __syncthreads();
    for (int p = tid; p < Hq * Hq; p += 256) {
        int r = p / Hq, j = p - r * Hq;
        double acc = 0.0;
#pragma unroll
        for (int c0 = 0; c0 < 128; c0 += 16) {
            float f = 0.f;
#pragma unroll
            for (int i = 0; i < 16; ++i) f = fmaf(sQ[r][c0 + i], sK[j][c0 + i], f);
            acc += (double)f;
        }
        sEx[r][j] = (float)(acc / SQRTD);
    }
    __syncthreads();
    int wv = tid >> 6, lane = tid & 63;
    for (int r = wv; r < Hq; r += 4) {
        float s = (lane < Hq) ? sEx[r][lane] : -1e30f;
        float mx = s;
        for (int o = 32; o > 0; o >>= 1) mx = fmaxf(mx, __shfl_xor(mx, o));
        float ex = (lane < Hq) ? (float)exp((double)(s - mx)) : 0.f;
        double ds = (double)ex;
        for (int o = 32; o > 0; o >>= 1) ds += __shfl_xor(ds, o);
        if (lane < Hq) sEx[r][lane] = ex;
        if (lane == 0) sInv[r] = 1.0 / ds;
    }
    __syncthreads();
    int d = tid & 127, rh = tid >> 7;
    for (int r = rh; r < Hq; r += 2) {
        double acc = 0.0;
        for (int c0 = 0; c0 < Hq; c0 += 16) {
            float f = 0.f;
            int ce = (c0 + 16 < Hq) ? c0 + 16 : Hq;
            for (int c = c0; c < ce; ++c) f = fmaf(sEx[r][c], sV[c * 128 + d], f);
            acc += (double)f;
        }
        Out[(long)b * ob_stride + (long)r * 128 + d] = (float)(acc * sInv[r]);
    }
    if (tail_src) {
        for (int idx = tid; idx < NEG1q * 128; idx += 256) {
            int rr = Hq + (idx >> 7), dd = idx & 127;
            Out[(long)b * ob_stride + (long)rr * 128 + dd] = tail_src[((long)(b * Sq + rr)) * 128 + dd];
        }
    }
}

// ---------------------------------------------------------------- fused final: user_pool + 2x mask_pool + gating
__global__ __launch_bounds__(128) void k_final_fused(
        const float* __restrict__ UT3, const float* __restrict__ score,
        const float* __restrict__ nc2, const float* __restrict__ gate,
        const int* __restrict__ hist_mask, const int* __restrict__ pos_mask, const int* __restrict__ neg_masks,
        const float* __restrict__ NC2, const float* __restrict__ wwW, const float* __restrict__ wwb,
        float* __restrict__ out) {
    int blk = blockIdx.x;
    int b = blk / NEG1q, g = blk % NEG1q;
    int tid = threadIdx.x;
    __shared__ float sEx[NPGq];
    __shared__ float sExU[Hq];
    __shared__ float redf[128];
    __shared__ double redd[128];

    float sv = (tid < Hq) ? score[b * Hq + tid] : -1e30f;
    redf[tid] = sv; __syncthreads();
    for (int d = 64; d > 0; d >>= 1) { if (tid < d) redf[tid] = fmaxf(redf[tid], redf[tid + d]); __syncthreads(); }
    float mxu = redf[0];
    float exu = (tid < Hq) ? (float)exp((double)(sv - mxu)) : 0.f;
    if (tid < Hq) sExU[tid] = exu;
    redd[tid] = (double)exu; __syncthreads();
    for (int d = 64; d > 0; d >>= 1) { if (tid < d) redd[tid] += redd[tid + d]; __syncthreads(); }
    double denu = redd[0];
    double accu = 0.0;
    for (int h = 0; h < Hq; ++h)
        accu += (double)sExU[h] * (double)UT3[((long)(b * Hq + h)) * 128 + tid];
    float ut = (float)(accu / denu);

    int base = b * NPGq;
    float seg_out[2];
    int segs[2] = {0, 1 + g};
#pragma unroll
    for (int si = 0; si < 2; ++si) {
        int s = segs[si];
        __syncthreads();
        float logit = -1e30f; int mk = 0;
        if (tid < NPGq) {
            int n = base + tid;
            mk = (s == 0) ? hist_mask[n] : (s == 1) ? pos_mask[n] : neg_masks[n * NEGq + (s - 2)];
            logit = (mk > 0) ? gate[n] : -1000000000.0f;
        }
        redf[tid] = logit; __syncthreads();
        for (int d = 64; d > 0; d >>= 1) { if (tid < d) redf[tid] = fmaxf(redf[tid], redf[tid + d]); __syncthreads(); }
        float mx = redf[0];
        float ex = 0.f;
        if (tid < NPGq && mk > 0) ex = (float)exp((double)(logit - mx));
        if (tid < NPGq) sEx[tid] = ex;
        redd[tid] = (double)ex; __syncthreads();
        for (int d = 64; d > 0; d >>= 1) { if (tid < d) redd[tid] += redd[tid + d]; __syncthreads(); }
        double den = redd[0] + 1e-16;
        double acc = 0.0;
        for (int c0 = 0; c0 < NPGq; c0 += 16) {
            float f = 0.f;
#pragma unroll
            for (int c = 0; c < 16; ++c)
                f = fmaf(sEx[c0 + c], nc2[((long)(base + c0 + c)) * 128 + tid], f);
            acc += (double)f;
        }
        seg_out[si] = (float)(acc / den);
    }
    float ug = seg_out[0], tg = seg_out[1];
    float tt = NC2[(long)(b * Sq + Hq + g) * 128 + tid];
    double w0 = (double)wwW[tid], w1 = (double)wwW[128 + tid];

    __syncthreads();
    redd[tid] = (double)ug * w0 + (double)ut * w1;
    __syncthreads();
    for (int d = 64; d > 0; d >>= 1) { if (tid < d) redd[tid] += redd[tid + d]; __syncthreads(); }
    float su = (float)redd[0] + wwb[0];
    float uwf = (float)(1.0 / (1.0 + exp(-(double)su)));
    __syncthreads();

    redd[tid] = (double)tg * w0 + (double)tt * w1;
    __syncthreads();
    for (int d = 64; d > 0; d >>= 1) { if (tid < d) redd[tid] += redd[tid + d]; __syncthreads(); }
    float st = (float)redd[0] + wwb[0];
    float twf = (float)(1.0 / (1.0 + exp(-(double)st)));
    __syncthreads();

    float uh = uwf * ug + (1.f - uwf) * ut;
    float th = twf * tg + (1.f - twf) * tt;
    redd[tid] = (double)uh * (double)th;
    __syncthreads();
    for (int d = 64; d > 0; d >>= 1) { if (tid < d) redd[tid] += redd[tid + d]; __syncthreads(); }
    if (tid == 0) out[blk] = (float)redd[0];
}

// ================================================================ launch
extern "C" void kernel_launch(void* const* d_in, const int* in_sizes, int n_in,
                              void* d_out, int out_size, void* d_ws, size_t ws_size,
                              hipStream_t stream) {
    const int*   nodes      = (const int*)d_in[0];
    const int*   ei_src     = (const int*)d_in[1];
    const int*   ei_dst     = ei_src + Eq;
    const int*   bi_news    = (const int*)d_in[2];
    const int*   bi_node    = bi_news + BEq;
    const int*   hist_mask  = (const int*)d_in[4];
    const int*   pos_mask   = (const int*)d_in[5];
    const int*   neg_masks  = (const int*)d_in[6];
    const int*   hist_seqs  = (const int*)d_in[7];
    const int*   hist_lens  = (const int*)d_in[8];
    const int*   pos_seq    = (const int*)d_in[9];
    const int*   pos_len    = (const int*)d_in[10];
    const int*   neg_seqs   = (const int*)d_in[11];
    const int*   neg_lens   = (const int*)d_in[12];
    const int*   title_tok  = (const int*)d_in[13];
    const float* ent_emb    = (const float*)d_in[14];
    const float* word_emb   = (const float*)d_in[15];
    const float* te_W  = (const float*)d_in[16];
    const float* te_b  = (const float*)d_in[17];
    const float* te_v  = (const float*)d_in[18];
    const float* ue1_Wq = (const float*)d_in[19];
    const float* ue1_Wk = (const float*)d_in[20];
    const float* ue1_Wv = (const float*)d_in[21];
    const float* ue2_Wq = (const float*)d_in[22];
    const float* ue2_Wk = (const float*)d_in[23];
    const float* ue2_Wv = (const float*)d_in[24];
    const float* ue3_Wq = (const float*)d_in[25];
    const float* ue3_Wk = (const float*)d_in[26];
    const float* ue3_Wv = (const float*)d_in[27];
    const float* g1_W  = (const float*)d_in[28];
    const float* g1_as = (const float*)d_in[29];
    const float* g1_ad = (const float*)d_in[30];
    const float* g2_W  = (const float*)d_in[31];
    const float* g2_as = (const float*)d_in[32];
    const float* g2_ad = (const float*)d_in[33];
    const float* cg1_Ws = (const float*)d_in[34];
    const float* cg1_Wd = (const float*)d_in[35];
    const float* cg1_as = (const float*)d_in[36];
    const float* cg1_ad = (const float*)d_in[37];
    const float* cg2_Ws = (const float*)d_in[38];
    const float* cg2_Wd = (const float*)d_in[39];
    const float* cg2_as = (const float*)d_in[40];
    const float* cg2_ad = (const float*)d_in[41];
    const float* sa_W  = (const float*)d_in[42];
    const float* sa_b  = (const float*)d_in[43];
    const float* sa_v  = (const float*)d_in[44];
    const float* gate_W = (const float*)d_in[45];
    const float* gate_b = (const float*)d_in[46];
    const float* ww_W  = (const float*)d_in[47];
    const float* ww_b  = (const float*)d_in[48];
    float* out = (float*)d_out;

    char* p = (char*)d_ws;
    auto alloc = [&](size_t bytes) -> void* {
        void* r = (void*)p;
        p += (bytes + 255) & ~(size_t)255;
        return r;
    };
    int* g_off  = (int*)alloc((Nq + 1) * 4);
    int* bn_off = (int*)alloc((Nq + 1) * 4);
    int* bw_off = (int*)alloc((NEWSq + 1) * 4);
    int* g_src  = (int*)alloc(Eq * 4);
    int* bn_src = (int*)alloc(BEq * 4);
    int* bw_src = (int*)alloc(BEq * 4);
    int* cnt3   = (int*)alloc((2 * Nq + NEWSq) * 4);
    int* cur3   = (int*)alloc((2 * Nq + NEWSq) * 4);
    int* cg  = cnt3, *cbn = cnt3 + Nq, *cbw = cnt3 + 2 * Nq;
    int* curg = cur3, *curbn = cur3 + Nq, *curbw = cur3 + 2 * Nq;

    float* wscore  = (float*)alloc(WVOCq * 4);
    float* UTraw   = (float*)alloc((size_t)Bq * Hq * 128 * 4);
    float* UT3     = (float*)alloc((size_t)Bq * Hq * 128 * 4);
    float* news1   = (float*)alloc((size_t)NEWSq * 128 * 4);
    float* NC1     = (float*)alloc((size_t)NEWSq * 128 * 4);
    float* news2   = (float*)alloc((size_t)NEWSq * 128 * 4);
    float* NC2     = (float*)alloc((size_t)NEWSq * 128 * 4);
    float* newsS1  = (float*)alloc((size_t)NEWSq * 128 * 4);   // hs_news
    float* v0      = (float*)alloc((size_t)Nq * 128 * 4);
    float* v1      = (float*)alloc((size_t)Nq * 128 * 4);
    float* nc1     = (float*)alloc((size_t)Nq * 128 * 4);
    float* v2      = (float*)alloc((size_t)Nq * 128 * 4);
    float* nc2     = (float*)alloc((size_t)Nq * 128 * 4);
    float* nodeS1  = (float*)alloc((size_t)Nq * 128 * 4);      // hs_node / GAT h
    float* qb      = (float*)alloc((size_t)Bq * Hq * 128 * 4);
    float* kb      = (float*)alloc((size_t)Bq * Hq * 128 * 4);
    float* vb      = (float*)alloc((size_t)Bq * Hq * 128 * 4);
    float* es_node = (float*)alloc(Nq * 4);
    float* ed_node = (float*)alloc(Nq * 4);
    float* es_news = (float*)alloc(NEWSq * 4);
    float* gate    = (float*)alloc(Nq * 4);
    float* score_bh = (float*)alloc(Bq * Hq * 4);
    float* wdvec1  = (float*)alloc(128 * 4);
    float* wdvec2  = (float*)alloc(128 * 4);

    const int MH = Bq * Hq;          // 6400
    const int nbMH   = (MH + MMROWS - 1) / MMROWS;      // 200
    const int nbNode = (Nq + MMROWS - 1) / MMROWS;      // 320
    const int nbNews = (NEWSq + MMROWS - 1) / MMROWS;   // 220
    const int TOTE = Eq + 2 * BEq;                      // 220160
    const int BIG = 0x7fffffff;
    const int nCount = (TOTE + 255) / 256;              // 860
    const int nEmbed = (Nq * 32 + 255) / 256;           // 1280
    const int nWS    = (WVOCq + MMROWS - 1) / MMROWS;   // 1563

    auto mkjob = [](const float* A, const float* W, float* C, const float* q0, const float* q1,
                    float* o0, float* o1, int M, int end, int amap) {
        MMJob j; j.A = A; j.W = W; j.C = C; j.q0 = q0; j.q1 = q1; j.o0 = o0; j.o1 = o1;
        j.M = M; j.blk_end = end; j.amap = amap; return j;
    };
    auto mkea = [](const int* off, const int* srcs, const float* es, const float* ed,
                   const float* edvec, const float* Hsrc, const float* Xdst,
                   float* Out, int nseg, int mode) {
        EASet s; s.off = off; s.srcs = srcs; s.es = es; s.ed = ed; s.edvec = edvec;
        s.Hsrc = Hsrc; s.Xdst = Xdst; s.Out = Out; s.nseg = nseg; s.mode = mode; return s;
    };
    EASet eaNone = mkea(nullptr, nullptr, nullptr, nullptr, nullptr, nullptr, nullptr, nullptr, 0, 0);
    MMJob jNone = mkjob(nullptr, nullptr, nullptr, nullptr, nullptr, nullptr, nullptr, 0, BIG, 0);

    // L0: zero CSR counters
    hipMemsetAsync(cnt3, 0, (size_t)(2 * Nq + NEWSq) * 4, stream);
    // L1: count || embed || word-score || wdvec prep
    k_misc1<<<nCount + nEmbed + nWS + 1, 256, 0, stream>>>(
        ei_dst, bi_node, bi_news, cg, cbn, cbw,
        nodes, ent_emb, v0,
        word_emb, te_W, te_b, te_v, wscore,
        cg1_Wd, cg1_ad, wdvec1, cg2_Wd, cg2_ad, wdvec2,
        nCount, nEmbed, nWS);
    // L2: scan
    k_scan3<<<3, 1024, 0, stream>>>(cg, cbn, cbw, g_off, bn_off, bw_off, curg, curbn, curbw);
    // L3: scatter || title_pool
    k_misc2<<<nCount + (Bq * Sq) / 2, 256, 0, stream>>>(
        ei_src, ei_dst, bi_news, bi_node, curg, curbn, curbw, g_src, bn_src, bw_src,
        title_tok, wscore, word_emb,
        hist_seqs, hist_lens, pos_seq, pos_len, neg_seqs, neg_lens, UTraw, news1, nCount);

    // L4: QKV1 || GAT1 matmul
    {
        MMJobs js;
        js.j[0] = mkjob(UTraw, ue1_Wq, qb, nullptr, nullptr, nullptr, nullptr, MH, nbMH, 0);
        js.j[1] = mkjob(UTraw, ue1_Wk, kb, nullptr, nullptr, nullptr, nullptr, MH, 2 * nbMH, 0);
        js.j[2] = mkjob(UTraw, ue1_Wv, vb, nullptr, nullptr, nullptr, nullptr, MH, 3 * nbMH, 0);
        js.j[3] = mkjob(v0, g1_W, nodeS1, g1_as, g1_ad, es_node, ed_node, Nq, BIG, 0);
        k_mm_jobs<<<3 * nbMH + nbNode, 256, 0, stream>>>(js);
    }
    // L5: attn1
    k_self_attn<<<Bq, 256, 0, stream>>>(qb, kb, vb, news1, Sq * 128, nullptr);
    // L6: cross1 news-Ws matmul || edge_agg GAT1
    k_ea_mm<<<nbNews + (Nq + 3) / 4, 256, 0, stream>>>(
        mkjob(news1, cg1_Ws, newsS1, cg1_as, nullptr, es_news, nullptr, NEWSq, BIG, 0), nbNews,
        mkea(g_off, g_src, es_node, ed_node, nullptr, nodeS1, nullptr, v1, Nq, 0), eaNone);
    // L7: cross1 node-Ws matmul
    {
        MMJobs js;
        js.j[0] = mkjob(v1, cg1_Ws, nodeS1, cg1_as, nullptr, es_node, nullptr, Nq, BIG, 0);
        js.j[1] = js.j[2] = js.j[3] = jNone;
        k_mm_jobs<<<nbNode, 256, 0, stream>>>(js);
    }
    // L8: both cross1 edge_aggs (ed inline via wdvec1)
    k_edge_agg_w<<<(Nq + NEWSq + 3) / 4, 256, 0, stream>>>(
        mkea(bn_off, bn_src, es_news, nullptr, wdvec1, newsS1, v1, nc1, Nq, 1),
        mkea(bw_off, bw_src, es_node, nullptr, wdvec1, nodeS1, news1, NC1, NEWSq, 1),
        nullptr, nullptr, nullptr);

    // L9: QKV2 (NC1 gather) || GAT2 matmul
    {
        MMJobs js;
        js.j[0] = mkjob(NC1, ue2_Wq, qb, nullptr, nullptr, nullptr, nullptr, MH, nbMH, 1);
        js.j[1] = mkjob(NC1, ue2_Wk, kb, nullptr, nullptr, nullptr, nullptr, MH, 2 * nbMH, 1);
        js.j[2] = mkjob(NC1, ue2_Wv, vb, nullptr, nullptr, nullptr, nullptr, MH, 3 * nbMH, 1);
        js.j[3] = mkjob(nc1, g2_W, nodeS1, g2_as, g2_ad, es_node, ed_node, Nq, BIG, 0);
        k_mm_jobs<<<3 * nbMH + nbNode, 256, 0, stream>>>(js);
    }
    // L10: attn2 (+ tail copy)
    k_self_attn<<<Bq, 256, 0, stream>>>(qb, kb, vb, news2, Sq * 128, NC1);
    // L11: cross2 news-Ws matmul || edge_agg GAT2
    k_ea_mm<<<nbNews + (Nq + 3) / 4, 256, 0, stream>>>(
        mkjob(news2, cg2_Ws, newsS1, cg2_as, nullptr, es_news, nullptr, NEWSq, BIG, 0), nbNews,
        mkea(g_off, g_src, es_node, ed_node, nullptr, nodeS1, nullptr, v2, Nq, 0), eaNone);
    // L12: cross2 node-Ws matmul
    {
        MMJobs js;
        js.j[0] = mkjob(v2, cg2_Ws, nodeS1, cg2_as, nullptr, es_node, nullptr, Nq, BIG, 0);
        js.j[1] = js.j[2] = js.j[3] = jNone;
        k_mm_jobs<<<nbNode, 256, 0, stream>>>(js);
    }
    // L13: both cross2 edge_aggs (ed inline via wdvec2; + fused gate)
    k_edge_agg_w<<<(Nq + NEWSq + 3) / 4, 256, 0, stream>>>(
        mkea(bn_off, bn_src, es_news, nullptr, wdvec2, newsS1, v2, nc2, Nq, 1),
        mkea(bw_off, bw_src, es_node, nullptr, wdvec2, nodeS1, news2, NC2, NEWSq, 1),
        gate_W, gate_b, gate);

    // L14: QKV3 (NC2 gather)
    {
        MMJobs js;
        js.j[0] = mkjob(NC2, ue3_Wq, qb, nullptr, nullptr, nullptr, nullptr, MH, nbMH, 1);
        js.j[1] = mkjob(NC2, ue3_Wk, kb, nullptr, nullptr, nullptr, nullptr, MH, 2 * nbMH, 1);
        js.j[2] = mkjob(NC2, ue3_Wv, vb, nullptr, nullptr, nullptr, nullptr, MH, 3 * nbMH, 1);
        js.j[3] = jNone;
        k_mm_jobs<<<3 * nbMH, 256, 0, stream>>>(js);
    }
    // L15: attn3
    k_self_attn<<<Bq, 256, 0, stream>>>(qb, kb, vb, UT3, Hq * 128, nullptr);
    // L16: sa tanh-dot
    k_mm_tanh<<<nbMH, 256, 0, stream>>>(UT3, sa_W, MH, sa_b, sa_v, score_bh);
    // L17: fused final
    k_final_fused<<<Bq * NEG1q, 128, 0, stream>>>(UT3, score_bh, nc2, gate,
        hist_mask, pos_mask, neg_masks, NC2, ww_W, ww_b, out);
}

// Round 9
// 640.271 us; speedup vs baseline: 1.0338x; 1.0338x over previous
//
#include <hip/hip_runtime.h>
#include <math.h>

#define Bq    128
#define Dq    128
#define Hq    50
#define NEGq  4
#define Lq    30
#define Sq    55      // H + 1 + NEG
#define NPGq  80
#define Nq    10240   // B * NPG
#define Eq    163840  // N * 16
#define NEWSq 7040    // B * S
#define BEq   28160   // NEWS * 4
#define WVOCq 50000
#define NEG1q 5

__device__ __forceinline__ float leaky_f(float x) { return x > 0.f ? x : 0.2f * x; }

// ---------------------------------------------------------------- matmul core (R6-proven)
#define MMROWS 32

#define MM4(RR, CC, WC) \
    f[RR][CC] = fmaf(a.x, w0.WC, f[RR][CC]); \
    f[RR][CC] = fmaf(a.y, w1.WC, f[RR][CC]); \
    f[RR][CC] = fmaf(a.z, w2.WC, f[RR][CC]); \
    f[RR][CC] = fmaf(a.w, w3.WC, f[RR][CC]);

__device__ __forceinline__ void mm_compute(float* sW, float (*sA)[32],
        const float* __restrict__ A, const float* __restrict__ W,
        int M, int r0, int amap, double acc[4][4]) {
    int tid = threadIdx.x;
    int tx = tid & 31;
    int ty = tid >> 5;
    int j0 = tx * 4;
#pragma unroll
    for (int rr = 0; rr < 4; ++rr)
#pragma unroll
        for (int cc = 0; cc < 4; ++cc) acc[rr][cc] = 0.0;

    for (int ks = 0; ks < 4; ++ks) {
        __syncthreads();
        const float4* W4 = (const float4*)(W + ks * 32 * 128);
        float4* sW4 = (float4*)sW;
#pragma unroll
        for (int i = tid; i < 32 * 32; i += 256) sW4[i] = W4[i];
        {
            int r = tid >> 3, c4 = tid & 7;
            int gr = r0 + r;
            float4 v = make_float4(0.f, 0.f, 0.f, 0.f);
            if (gr < M) {
                long pr = amap ? (long)((gr / Hq) * Sq + gr % Hq) : (long)gr;
                v = *(const float4*)(A + pr * 128 + ks * 32 + c4 * 4);
            }
            *(float4*)&sA[r][c4 * 4] = v;
        }
        __syncthreads();
        float f[4][4];
#pragma unroll
        for (int rr = 0; rr < 4; ++rr)
#pragma unroll
            for (int cc = 0; cc < 4; ++cc) f[rr][cc] = 0.f;
#pragma unroll
        for (int k = 0; k < 32; k += 4) {
            float4 w0 = *(const float4*)&sW[(k + 0) * 128 + j0];
            float4 w1 = *(const float4*)&sW[(k + 1) * 128 + j0];
            float4 w2 = *(const float4*)&sW[(k + 2) * 128 + j0];
            float4 w3 = *(const float4*)&sW[(k + 3) * 128 + j0];
#pragma unroll
            for (int rr = 0; rr < 4; ++rr) {
                float4 a = *(const float4*)&sA[ty * 4 + rr][k];
                MM4(rr, 0, x) MM4(rr, 1, y) MM4(rr, 2, z) MM4(rr, 3, w)
            }
        }
#pragma unroll
        for (int rr = 0; rr < 4; ++rr)
#pragma unroll
            for (int cc = 0; cc < 4; ++cc) acc[rr][cc] += (double)f[rr][cc];
    }
}

// tanh-dot epilogue body (word-score)
__device__ __forceinline__ void mm_tanh_body(float* sW, float (*sA)[32],
        const float* __restrict__ A, const float* __restrict__ W, int M, int r0,
        const float* __restrict__ q0, const float* __restrict__ q1, float* __restrict__ o0) {
    double acc[4][4];
    mm_compute(sW, sA, A, W, M, r0, 0, acc);
    int tid = threadIdx.x, tx = tid & 31, ty = tid >> 5;
    int j0 = tx * 4;
    float q0c[4], q1c[4];
#pragma unroll
    for (int cc = 0; cc < 4; ++cc) { q0c[cc] = q0[j0 + cc]; q1c[cc] = q1[j0 + cc]; }
#pragma unroll
    for (int rr = 0; rr < 4; ++rr) {
        int r = r0 + ty * 4 + rr;
        double s = 0.0;
#pragma unroll
        for (int cc = 0; cc < 4; ++cc) {
            float t = (float)acc[rr][cc] + q0c[cc];
            s += (double)tanhf(t) * (double)q1c[cc];
        }
        for (int o = 16; o > 0; o >>= 1) s += __shfl_xor(s, o);
        if ((tid & 31) == 0 && r < M) o0[r] = (float)s;
    }
}

// ---- generic job-table matmul
struct MMJob {
    const float* A; const float* W; float* C;
    const float* q0; const float* q1;
    float* o0; float* o1;
    int M; int blk_end; int amap;
};
struct MMJobs { MMJob j[4]; };

__device__ __forceinline__ void mm_job_body(float* sW, float (*sA)[32], MMJob J, int r0) {
    double acc[4][4];
    mm_compute(sW, sA, J.A, J.W, J.M, r0, J.amap, acc);
    int tid = threadIdx.x, tx = tid & 31, ty = tid >> 5;
    int j0 = tx * 4;
    if (J.C) {
#pragma unroll
        for (int rr = 0; rr < 4; ++rr) {
            int r = r0 + ty * 4 + rr;
            if (r < J.M) {
                float4 o = make_float4((float)acc[rr][0], (float)acc[rr][1],
                                       (float)acc[rr][2], (float)acc[rr][3]);
                *(float4*)&J.C[(long)r * 128 + j0] = o;
            }
        }
    }
    if (J.o0) {
        float q0c[4], q1c[4];
        bool two = (J.q1 != nullptr);
#pragma unroll
        for (int cc = 0; cc < 4; ++cc) {
            q0c[cc] = J.q0[j0 + cc];
            q1c[cc] = two ? J.q1[j0 + cc] : 0.f;
        }
#pragma unroll
        for (int rr = 0; rr < 4; ++rr) {
            int r = r0 + ty * 4 + rr;
            double d0 = 0.0, d1 = 0.0;
#pragma unroll
            for (int cc = 0; cc < 4; ++cc) {
                double c = (double)(float)acc[rr][cc];
                d0 += c * (double)q0c[cc];
                d1 += c * (double)q1c[cc];
            }
            for (int o = 16; o > 0; o >>= 1) {
                d0 += __shfl_xor(d0, o);
                if (two) d1 += __shfl_xor(d1, o);
            }
            if ((tid & 31) == 0 && r < J.M) {
                J.o0[r] = (float)d0;
                if (two) J.o1[r] = (float)d1;
            }
        }
    }
}

__global__ __launch_bounds__(256) void k_mm_jobs(MMJobs js) {
    __shared__ float sW[32 * 128];
    __shared__ float sA[MMROWS][32];
    int bid = blockIdx.x;
    int ji = 0, blk0 = 0;
#pragma unroll
    for (int t = 0; t < 3; ++t)
        if (bid >= js.j[t].blk_end) { ji = t + 1; blk0 = js.j[t].blk_end; }
    mm_job_body(sW, sA, js.j[ji], (bid - blk0) * MMROWS);
}

// ---------------------------------------------------------------- misc1: count || embed || word-score || wdvec || Mprep
struct MPrep { const float* wq0; const float* wk0; float* m0;
               const float* wq1; const float* wk1; float* m1;
               const float* wq2; const float* wk2; float* m2; };

__global__ __launch_bounds__(256) void k_misc1(
        const int* __restrict__ ei_dst, const int* __restrict__ bi_node, const int* __restrict__ bi_news,
        int* __restrict__ cg, int* __restrict__ cbn, int* __restrict__ cbw,
        const int* __restrict__ nodes, const float* __restrict__ ent, float* __restrict__ v0,
        const float* __restrict__ wemb, const float* __restrict__ teW,
        const float* __restrict__ teb, const float* __restrict__ tev, float* __restrict__ wscore,
        const float* __restrict__ Wd1, const float* __restrict__ ad1, float* __restrict__ wdvec1,
        const float* __restrict__ Wd2, const float* __restrict__ ad2, float* __restrict__ wdvec2,
        MPrep mp, int n_count, int n_embed, int n_ws) {
    __shared__ float sW[32 * 128];
    __shared__ float sA[MMROWS][32];
    int blk = blockIdx.x;
    if (blk < n_count) {
        int e = blk * 256 + threadIdx.x;
        if (e < Eq) atomicAdd(&cg[ei_dst[e]], 1);
        else if (e < Eq + BEq) atomicAdd(&cbn[bi_node[e - Eq]], 1);
        else if (e < Eq + 2 * BEq) atomicAdd(&cbw[bi_news[e - Eq - BEq]], 1);
    } else if (blk < n_count + n_embed) {
        int i = (blk - n_count) * 256 + threadIdx.x;
        if (i < Nq * 32) {
            int r = i >> 5, d = i & 31;
            ((float4*)v0)[i] = ((const float4*)(ent + (long)nodes[r] * 128))[d];
        }
    } else if (blk < n_count + n_embed + n_ws) {
        int r0 = (blk - n_count - n_embed) * MMROWS;
        mm_tanh_body(sW, sA, wemb, teW, WVOCq, r0, teb, tev, wscore);
    } else if (blk == n_count + n_embed + n_ws) {
        // wdvec[k] = sum_j Wd[k][j] * ad[j]  (f64)
        int t = threadIdx.x;
        const float* Wd = (t < 128) ? Wd1 : Wd2;
        const float* ad = (t < 128) ? ad1 : ad2;
        float* ov = (t < 128) ? wdvec1 : wdvec2;
        int kk = t & 127;
        double s = 0.0;
        for (int j = 0; j < 128; ++j)
            s += (double)Wd[kk * 128 + j] * (double)ad[j];
        ov[kk] = (float)s;
    } else {
        // Mprep: M_l[a][b] = f32( sum_c Wq[a][c] * Wk[b][c] )  (f64 dot)
        int idx = (blk - (n_count + n_embed + n_ws + 1)) * 256 + threadIdx.x;
        int layer = idx >> 14;          // /16384
        int o = idx & 16383;
        int a = o >> 7, b2 = o & 127;
        const float* Wq = (layer == 0) ? mp.wq0 : (layer == 1) ? mp.wq1 : mp.wq2;
        const float* Wk = (layer == 0) ? mp.wk0 : (layer == 1) ? mp.wk1 : mp.wk2;
        float* Mo       = (layer == 0) ? mp.m0  : (layer == 1) ? mp.m1  : mp.m2;
        double s = 0.0;
        for (int c = 0; c < 128; ++c)
            s += (double)Wq[a * 128 + c] * (double)Wk[b2 * 128 + c];
        Mo[a * 128 + b2] = (float)s;
    }
}

// ---------------------------------------------------------------- scan (3 blocks)
__global__ __launch_bounds__(1024) void k_scan3(
        const int* __restrict__ cg, const int* __restrict__ cbn, const int* __restrict__ cbw,
        int* __restrict__ og, int* __restrict__ obn, int* __restrict__ obw,
        int* __restrict__ curg, int* __restrict__ curbn, int* __restrict__ curbw) {
    __shared__ int part[1024];
    const int* cnt; int* off; int* cur; int n;
    if (blockIdx.x == 0)      { cnt = cg;  off = og;  cur = curg;  n = Nq; }
    else if (blockIdx.x == 1) { cnt = cbn; off = obn; cur = curbn; n = Nq; }
    else                      { cnt = cbw; off = obw; cur = curbw; n = NEWSq; }
    int tid = threadIdx.x;
    int chunk = (n + 1023) >> 10;
    int s0 = tid * chunk;
    int s1 = s0 + chunk; if (s1 > n) s1 = n;
    int s = 0;
    for (int i = s0; i < s1; ++i) s += cnt[i];
    part[tid] = s;
    __syncthreads();
    for (int d = 1; d < 1024; d <<= 1) {
        int v = (tid >= d) ? part[tid - d] : 0;
        __syncthreads();
        part[tid] += v;
        __syncthreads();
    }
    int base = (tid > 0) ? part[tid - 1] : 0;
    for (int i = s0; i < s1; ++i) { off[i] = base; cur[i] = base; base += cnt[i]; }
    if (tid == 0) off[n] = part[1023];
}

// ---------------------------------------------------------------- misc2: scatter || title-pool
__global__ __launch_bounds__(256) void k_misc2(
        const int* __restrict__ ei_src, const int* __restrict__ ei_dst,
        const int* __restrict__ bi_news, const int* __restrict__ bi_node,
        int* __restrict__ curg, int* __restrict__ curbn, int* __restrict__ curbw,
        int* __restrict__ g_out, int* __restrict__ bn_out, int* __restrict__ bw_out,
        const int* __restrict__ title_tok, const float* __restrict__ wscore,
        const float* __restrict__ wemb,
        const int* __restrict__ hist_seqs, const int* __restrict__ hist_lens,
        const int* __restrict__ pos_seq, const int* __restrict__ pos_len,
        const int* __restrict__ neg_seqs, const int* __restrict__ neg_lens,
        float* __restrict__ UTraw, float* __restrict__ news1, int n_scatter) {
    __shared__ int tok[2][Lq];
    __shared__ float wgt[2][Lq];
    __shared__ double sden[2];
    int blk = blockIdx.x;
    if (blk < n_scatter) {
        int e = blk * 256 + threadIdx.x;
        if (e < Eq) {
            int slot = atomicAdd(&curg[ei_dst[e]], 1);
            g_out[slot] = ei_src[e];
        } else if (e < Eq + BEq) {
            int i = e - Eq;
            int slot = atomicAdd(&curbn[bi_node[i]], 1);
            bn_out[slot] = bi_news[i];
        } else if (e < Eq + 2 * BEq) {
            int i = e - Eq - BEq;
            int slot = atomicAdd(&curbw[bi_news[i]], 1);
            bw_out[slot] = bi_node[i];
        }
        return;
    }
    int half = threadIdx.x >> 7;
    int tid = threadIdx.x & 127;
    int t = (blk - n_scatter) * 2 + half;
    int b = t / Sq, s = t % Sq;
    int nid, len; float* dst;
    if (s < Hq)       { nid = hist_seqs[b * Hq + s]; len = hist_lens[b * Hq + s]; dst = UTraw + (long)(b * Hq + s) * 128; }
    else if (s == Hq) { nid = pos_seq[b];            len = pos_len[b];            dst = news1 + (long)t * 128; }
    else { int g = s - Hq - 1; nid = neg_seqs[b * NEGq + g]; len = neg_lens[b * NEGq + g]; dst = news1 + (long)t * 128; }

    if (tid < Lq) tok[half][tid] = title_tok[(long)nid * Lq + tid];
    __syncthreads();
    if (tid < 64) {
        float sc = (tid < len) ? wscore[tok[half][tid]] : -1e30f;
        float mx = sc;
        for (int o = 32; o > 0; o >>= 1) mx = fmaxf(mx, __shfl_xor(mx, o));
        float e = (tid < len) ? (float)exp((double)(sc - mx)) : 0.f;
        if (tid < Lq) wgt[half][tid] = e;
        double ds = (double)e;
        for (int o = 32; o > 0; o >>= 1) ds += __shfl_xor(ds, o);
        if (tid == 0) sden[half] = ds;
    }
    __syncthreads();
    double den = sden[half];
    double acc = 0.0;
    for (int l = 0; l < len; ++l)
        acc += (double)wgt[half][l] * (double)wemb[(long)tok[half][l] * 128 + tid];
    dst[tid] = (float)(acc / den);
}

// ---------------------------------------------------------------- edge aggregation structures
#define WMAXK 128
struct EASet {
    const int* off; const int* srcs;
    const float* es; const float* ed;     // ed: per-seg scalar array
    const float* edvec;                   // OR inline dot Xdst row . edvec
    const float* Hsrc; const float* Xdst;
    float* Out; int nseg; int mode;
};

// 64-lane wave per segment (main graph, avg degree 16)
__device__ __forceinline__ void ea_body(EASet S, int n, int wv, int lane,
        int (*sSrc)[WMAXK], float (*sE)[WMAXK]) {
    int s0 = S.off[n], k = S.off[n + 1] - s0;
    int d0 = lane * 2;
    float o0, o1;
    float2 xres = make_float2(0.f, 0.f);
    if (S.mode) xres = *(const float2*)&S.Xdst[(long)n * 128 + d0];
    if (k == 0) {
        o0 = S.mode ? xres.x : 0.f;
        o1 = S.mode ? xres.y : 0.f;
    } else {
        float edn;
        if (S.edvec) {
            double pp = (double)xres.x * (double)S.edvec[d0] + (double)xres.y * (double)S.edvec[d0 + 1];
            for (int o = 32; o > 0; o >>= 1) pp += __shfl_xor(pp, o);
            edn = (float)pp;
        } else {
            edn = S.ed[n];
        }
        float mloc = -1e30f;
        for (int j = lane; j < k; j += 64) {
            int sidx = S.srcs[s0 + j];
            float e = leaky_f(S.es[sidx] + edn);
            if (j < WMAXK) { sSrc[wv][j] = sidx; sE[wv][j] = e; }
            mloc = fmaxf(mloc, e);
        }
        for (int o = 32; o > 0; o >>= 1) mloc = fmaxf(mloc, __shfl_xor(mloc, o));
        float m = mloc;
        double dloc = 0.0;
        for (int j = lane; j < k; j += 64) {
            float e = (j < WMAXK) ? sE[wv][j] : leaky_f(S.es[S.srcs[s0 + j]] + edn);
            float ex = (float)exp((double)(e - m));
            if (j < WMAXK) sE[wv][j] = ex;
            dloc += (double)ex;
        }
        for (int o = 32; o > 0; o >>= 1) dloc += __shfl_xor(dloc, o);
        double den = dloc + 1e-16;
        for (int j = lane; j < k && j < WMAXK; j += 64)
            sE[wv][j] = (float)((double)sE[wv][j] / den);
        double a0 = 0.0, a1 = 0.0;
        for (int j = 0; j < k; ++j) {
            float alpha; int sidx;
            if (j < WMAXK) { alpha = sE[wv][j]; sidx = sSrc[wv][j]; }
            else {
                sidx = S.srcs[s0 + j];
                float e = leaky_f(S.es[sidx] + edn);
                float ex = (float)exp((double)(e - m));
                alpha = (float)((double)ex / den);
            }
            float2 h = *(const float2*)&S.Hsrc[(long)sidx * 128 + d0];
            a0 += (double)alpha * (double)h.x;
            a1 += (double)alpha * (double)h.y;
        }
        float v0f = (float)a0, v1f = (float)a1;
        o0 = (v0f > 0.f) ? v0f : (float)expm1((double)v0f);
        o1 = (v1f > 0.f) ? v1f : (float)expm1((double)v1f);
        if (S.mode) { o0 += xres.x; o1 += xres.y; }
    }
    *(float2*)&S.Out[(long)n * 128 + d0] = make_float2(o0, o1);
}

// ---- combined: one MM job (blocks [0,nMM)) || 64-lane edge-agg (rest)
__global__ __launch_bounds__(256) void k_ea_mm(MMJob mj, int nMM, EASet a) {
    __shared__ float sW[32 * 128];
    __shared__ float sA[MMROWS][32];
    __shared__ int   sSrc[4][WMAXK];
    __shared__ float sE[4][WMAXK];
    int blk = blockIdx.x;
    if (blk < nMM) {
        mm_job_body(sW, sA, mj, blk * MMROWS);
        return;
    }
    int wv = threadIdx.x >> 6, lane = threadIdx.x & 63;
    int g = (blk - nMM) * 4 + wv;
    if (g >= a.nseg) return;
    ea_body(a, g, wv, lane, sSrc, sE);
}

// ---- 16-lane teams (bi-graphs, avg degree 3-4): 16 segments per 256-thread block
#define TMAXK 32
__global__ __launch_bounds__(256) void k_ea16(EASet a, EASet b,
        const float* __restrict__ gW, const float* __restrict__ gb, float* __restrict__ gout) {
    __shared__ int   sS[16][TMAXK];
    __shared__ float sE[16][TMAXK];
    int team = threadIdx.x >> 4, t = threadIdx.x & 15;
    int g = blockIdx.x * 16 + team;
    if (g >= a.nseg + b.nseg) return;
    bool isA = g < a.nseg;
    EASet S = isA ? a : b;
    int n = isA ? g : g - a.nseg;
    int s0 = S.off[n], k = S.off[n + 1] - s0;
    int d0 = t * 8;
    float4 x0 = make_float4(0.f, 0.f, 0.f, 0.f), x1 = x0;
    if (S.mode) {
        x0 = *(const float4*)&S.Xdst[(long)n * 128 + d0];
        x1 = *(const float4*)&S.Xdst[(long)n * 128 + d0 + 4];
    }
    float o[8];
    if (k == 0) {
        o[0] = x0.x; o[1] = x0.y; o[2] = x0.z; o[3] = x0.w;
        o[4] = x1.x; o[5] = x1.y; o[6] = x1.z; o[7] = x1.w;
        if (!S.mode) { for (int i = 0; i < 8; ++i) o[i] = 0.f; }
    } else {
        // edn = Xdst row . edvec (f64)
        double pp = (double)x0.x * (double)S.edvec[d0 + 0] + (double)x0.y * (double)S.edvec[d0 + 1]
                  + (double)x0.z * (double)S.edvec[d0 + 2] + (double)x0.w * (double)S.edvec[d0 + 3]
                  + (double)x1.x * (double)S.edvec[d0 + 4] + (double)x1.y * (double)S.edvec[d0 + 5]
                  + (double)x1.z * (double)S.edvec[d0 + 6] + (double)x1.w * (double)S.edvec[d0 + 7];
        for (int off = 8; off > 0; off >>= 1) pp += __shfl_xor(pp, off, 16);
        float edn = (float)pp;
        float mloc = -1e30f;
        for (int j = t; j < k; j += 16) {
            int sidx = S.srcs[s0 + j];
            float e = leaky_f(S.es[sidx] + edn);
            if (j < TMAXK) { sS[team][j] = sidx; sE[team][j] = e; }
            mloc = fmaxf(mloc, e);
        }
        for (int off = 8; off > 0; off >>= 1) mloc = fmaxf(mloc, __shfl_xor(mloc, off, 16));
        float m = mloc;
        double dloc = 0.0;
        for (int j = t; j < k; j += 16) {
            float e = (j < TMAXK) ? sE[team][j] : leaky_f(S.es[S.srcs[s0 + j]] + edn);
            float ex = (float)exp((double)(e - m));
            if (j < TMAXK) sE[team][j] = ex;
            dloc += (double)ex;
        }
        for (int off = 8; off > 0; off >>= 1) dloc += __shfl_xor(dloc, off, 16);
        double den = dloc + 1e-16;
        for (int j = t; j < k && j < TMAXK; j += 16)
            sE[team][j] = (float)((double)sE[team][j] / den);
        double acc[8];
#pragma unroll
        for (int i = 0; i < 8; ++i) acc[i] = 0.0;
        for (int j = 0; j < k; ++j) {
            float alpha; int sidx;
            if (j < TMAXK) { alpha = sE[team][j]; sidx = sS[team][j]; }
            else {
                sidx = S.srcs[s0 + j];
                float e = leaky_f(S.es[sidx] + edn);
                float ex = (float)exp((double)(e - m));
                alpha = (float)((double)ex / den);
            }
            float4 h0 = *(const float4*)&S.Hsrc[(long)sidx * 128 + d0];
            float4 h1 = *(const float4*)&S.Hsrc[(long)sidx * 128 + d0 + 4];
            acc[0] += (double)alpha * (double)h0.x; acc[1] += (double)alpha * (double)h0.y;
            acc[2] += (double)alpha * (double)h0.z; acc[3] += (double)alpha * (double)h0.w;
            acc[4] += (double)alpha * (double)h1.x; acc[5] += (double)alpha * (double)h1.y;
            acc[6] += (double)alpha * (double)h1.z; acc[7] += (double)alpha * (double)h1.w;
        }
        const float xr[8] = {x0.x, x0.y, x0.z, x0.w, x1.x, x1.y, x1.z, x1.w};
#pragma unroll
        for (int i = 0; i < 8; ++i) {
            float vf = (float)acc[i];
            o[i] = (vf > 0.f) ? vf : (float)expm1((double)vf);
            if (S.mode) o[i] += xr[i];
        }
    }
    *(float4*)&S.Out[(long)n * 128 + d0]     = make_float4(o[0], o[1], o[2], o[3]);
    *(float4*)&S.Out[(long)n * 128 + d0 + 4] = make_float4(o[4], o[5], o[6], o[7]);
    if (isA && gout) {
        double part = 0.0;
#pragma unroll
        for (int i = 0; i < 8; ++i) part += (double)o[i] * (double)gW[d0 + i];
        for (int off = 8; off > 0; off >>= 1) part += __shfl_xor(part, off, 16);
        if (t == 0) gout[n] = (float)part + gb[0];
    }
}

// ---------------------------------------------------------------- self-attention (M-factored keys; optional sa-score epilogue)
__global__ __launch_bounds__(256) void k_self_attn(const float* __restrict__ XM, const float* __restrict__ X,
        const float* __restrict__ V, float* __restrict__ Out, int ob_stride,
        const float* __restrict__ tail_src, int xmap,
        const float* __restrict__ sa_bp, const float* __restrict__ sa_vp, float* __restrict__ score_out) {
    __shared__ float sQ[Hq][129];   // XM rows; reused for output rows in sa epilogue
    __shared__ float sX[Hq][129];   // raw input rows (keys)
    __shared__ float sV[Hq * 128];
    __shared__ float sEx[Hq][52];
    __shared__ double sInv[Hq];
    const double SQRTD = (double)11.3137085f;
    int b = blockIdx.x;
    int tid = threadIdx.x;
    const float* XMb = XM + (long)b * Hq * 128;
    const float* Vb = V + (long)b * Hq * 128;
    for (int idx = tid; idx < Hq * 128; idx += 256) {
        int r = idx >> 7, i = idx & 127;
        sQ[r][i] = XMb[idx];
        long xrow = xmap ? (long)(b * Sq + r) : (long)(b * Hq + r);
        sX[r][i] = X[xrow * 128 + i];
        sV[idx] = Vb[idx];
    }
    __syncthreads();
    for (int p = tid; p < Hq * Hq; p += 256) {
        int r = p / Hq, j = p - r * Hq;
        double acc = 0.0;
#pragma unroll
        for (int c0 = 0; c0 < 128; c0 += 16) {
            float f = 0.f;
#pragma unroll
            for (int i = 0; i < 16; ++i) f = fmaf(sQ[r][c0 + i], sX[j][c0 + i], f);
            acc += (double)f;
        }
        sEx[r][j] = (float)(acc / SQRTD);
    }
    __syncthreads();
    int wv = tid >> 6, lane = tid & 63;
    for (int r = wv; r < Hq; r += 4) {
        float s = (lane < Hq) ? sEx[r][lane] : -1e30f;
        float mx = s;
        for (int o = 32; o > 0; o >>= 1) mx = fmaxf(mx, __shfl_xor(mx, o));
        float ex = (lane < Hq) ? (float)exp((double)(s - mx)) : 0.f;
        double ds = (double)ex;
        for (int o = 32; o > 0; o >>= 1) ds += __shfl_xor(ds, o);
        if (lane < Hq) sEx[r][lane] = ex;
        if (lane == 0) sInv[r] = 1.0 / ds;
    }
    __syncthreads();
    int d = tid & 127, rh = tid >> 7;
    for (int r = rh; r < Hq; r += 2) {
        double acc = 0.0;
        for (int c0 = 0; c0 < Hq; c0 += 16) {
            float f = 0.f;
            int ce = (c0 + 16 < Hq) ? c0 + 16 : Hq;
            for (int c = c0; c < ce; ++c) f = fmaf(sEx[r][c], sV[c * 128 + d], f);
            acc += (double)f;
        }
        float ov = (float)(acc * sInv[r]);
        Out[(long)b * ob_stride + (long)r * 128 + d] = ov;
        if (score_out) sQ[r][d] = ov;
    }
    if (score_out) {
        __syncthreads();
        for (int r = wv; r < Hq; r += 4) {
            int c = lane * 2;
            float t0 = sQ[r][c] + sa_bp[c];
            float t1 = sQ[r][c + 1] + sa_bp[c + 1];
            double s = (double)tanhf(t0) * (double)sa_vp[c]
                     + (double)tanhf(t1) * (double)sa_vp[c + 1];
            for (int o = 32; o > 0; o >>= 1) s += __shfl_xor(s, o);
            if (lane == 0) score_out[b * Hq + r] = (float)s;
        }
    }
    if (tail_src) {
        for (int idx = tid; idx < NEG1q * 128; idx += 256) {
            int rr = Hq + (idx >> 7), dd = idx & 127;
            Out[(long)b * ob_stride + (long)rr * 128 + dd] = tail_src[((long)(b * Sq + rr)) * 128 + dd];
        }
    }
}

// ---------------------------------------------------------------- fused final
__global__ __launch_bounds__(128) void k_final_fused(
        const float* __restrict__ UT3, const float* __restrict__ score,
        const float* __restrict__ nc2, const float* __restrict__ gate,
        const int* __restrict__ hist_mask, const int* __restrict__ pos_mask, const int* __restrict__ neg_masks,
        const float* __restrict__ NC2, const float* __restrict__ wwW, const float* __restrict__ wwb,
        float* __restrict__ out) {
    int blk = blockIdx.x;
    int b = blk / NEG1q, g = blk % NEG1q;
    int tid = threadIdx.x;
    __shared__ float sEx[NPGq];
    __shared__ float sExU[Hq];
    __shared__ float redf[128];
    __shared__ double redd[128];

    float sv = (tid < Hq) ? score[b * Hq + tid] : -1e30f;
    redf[tid] = sv; __syncthreads();
    for (int d = 64; d > 0; d >>= 1) { if (tid < d) redf[tid] = fmaxf(redf[tid], redf[tid + d]); __syncthreads(); }
    float mxu = redf[0];
    float exu = (tid < Hq) ? (float)exp((double)(sv - mxu)) : 0.f;
    if (tid < Hq) sExU[tid] = exu;
    redd[tid] = (double)exu; __syncthreads();
    for (int d = 64; d > 0; d >>= 1) { if (tid < d) redd[tid] += redd[tid + d]; __syncthreads(); }
    double denu = redd[0];
    double accu = 0.0;
    for (int h = 0; h < Hq; ++h)
        accu += (double)sExU[h] * (double)UT3[((long)(b * Hq + h)) * 128 + tid];
    float ut = (float)(accu / denu);

    int base = b * NPGq;
    float seg_out[2];
    int segs[2] = {0, 1 + g};
#pragma unroll
    for (int si = 0; si < 2; ++si) {
        int s = segs[si];
        __syncthreads();
        float logit = -1e30f; int mk = 0;
        if (tid < NPGq) {
            int n = base + tid;
            mk = (s == 0) ? hist_mask[n] : (s == 1) ? pos_mask[n] : neg_masks[n * NEGq + (s - 2)];
            logit = (mk > 0) ? gate[n] : -1000000000.0f;
        }
        redf[tid] = logit; __syncthreads();
        for (int d = 64; d > 0; d >>= 1) { if (tid < d) redf[tid] = fmaxf(redf[tid], redf[tid + d]); __syncthreads(); }
        float mx = redf[0];
        float ex = 0.f;
        if (tid < NPGq && mk > 0) ex = (float)exp((double)(logit - mx));
        if (tid < NPGq) sEx[tid] = ex;
        redd[tid] = (double)ex; __syncthreads();
        for (int d = 64; d > 0; d >>= 1) { if (tid < d) redd[tid] += redd[tid + d]; __syncthreads(); }
        double den = redd[0] + 1e-16;
        double acc = 0.0;
        for (int c0 = 0; c0 < NPGq; c0 += 16) {
            float f = 0.f;
#pragma unroll
            for (int c = 0; c < 16; ++c)
                f = fmaf(sEx[c0 + c], nc2[((long)(base + c0 + c)) * 128 + tid], f);
            acc += (double)f;
        }
        seg_out[si] = (float)(acc / den);
    }
    float ug = seg_out[0], tg = seg_out[1];
    float tt = NC2[(long)(b * Sq + Hq + g) * 128 + tid];
    double w0 = (double)wwW[tid], w1 = (double)wwW[128 + tid];

    __syncthreads();
    redd[tid] = (double)ug * w0 + (double)ut * w1;
    __syncthreads();
    for (int d = 64; d > 0; d >>= 1) { if (tid < d) redd[tid] += redd[tid + d]; __syncthreads(); }
    float su = (float)redd[0] + wwb[0];
    float uwf = (float)(1.0 / (1.0 + exp(-(double)su)));
    __syncthreads();

    redd[tid] = (double)tg * w0 + (double)tt * w1;
    __syncthreads();
    for (int d = 64; d > 0; d >>= 1) { if (tid < d) redd[tid] += redd[tid + d]; __syncthreads(); }
    float st = (float)redd[0] + wwb[0];
    float twf = (float)(1.0 / (1.0 + exp(-(double)st)));
    __syncthreads();

    float uh = uwf * ug + (1.f - uwf) * ut;
    float th = twf * tg + (1.f - twf) * tt;
    redd[tid] = (double)uh * (double)th;
    __syncthreads();
    for (int d = 64; d > 0; d >>= 1) { if (tid < d) redd[tid] += redd[tid + d]; __syncthreads(); }
    if (tid == 0) out[blk] = (float)redd[0];
}

// ================================================================ launch
extern "C" void kernel_launch(void* const* d_in, const int* in_sizes, int n_in,
                              void* d_out, int out_size, void* d_ws, size_t ws_size,
                              hipStream_t stream) {
    const int*   nodes      = (const int*)d_in[0];
    const int*   ei_src     = (const int*)d_in[1];
    const int*   ei_dst     = ei_src + Eq;
    const int*   bi_news    = (const int*)d_in[2];
    const int*   bi_node    = bi_news + BEq;
    const int*   hist_mask  = (const int*)d_in[4];
    const int*   pos_mask   = (const int*)d_in[5];
    const int*   neg_masks  = (const int*)d_in[6];
    const int*   hist_seqs  = (const int*)d_in[7];
    const int*   hist_lens  = (const int*)d_in[8];
    const int*   pos_seq    = (const int*)d_in[9];
    const int*   pos_len    = (const int*)d_in[10];
    const int*   neg_seqs   = (const int*)d_in[11];
    const int*   neg_lens   = (const int*)d_in[12];
    const int*   title_tok  = (const int*)d_in[13];
    const float* ent_emb    = (const float*)d_in[14];
    const float* word_emb   = (const float*)d_in[15];
    const float* te_W  = (const float*)d_in[16];
    const float* te_b  = (const float*)d_in[17];
    const float* te_v  = (const float*)d_in[18];
    const float* ue1_Wq = (const float*)d_in[19];
    const float* ue1_Wk = (const float*)d_in[20];
    const float* ue1_Wv = (const float*)d_in[21];
    const float* ue2_Wq = (const float*)d_in[22];
    const float* ue2_Wk = (const float*)d_in[23];
    const float* ue2_Wv = (const float*)d_in[24];
    const float* ue3_Wq = (const float*)d_in[25];
    const float* ue3_Wk = (const float*)d_in[26];
    const float* ue3_Wv = (const float*)d_in[27];
    const float* g1_W  = (const float*)d_in[28];
    const float* g1_as = (const float*)d_in[29];
    const float* g1_ad = (const float*)d_in[30];
    const float* g2_W  = (const float*)d_in[31];
    const float* g2_as = (const float*)d_in[32];
    const float* g2_ad = (const float*)d_in[33];
    const float* cg1_Ws = (const float*)d_in[34];
    const float* cg1_Wd = (const float*)d_in[35];
    const float* cg1_as = (const float*)d_in[36];
    const float* cg1_ad = (const float*)d_in[37];
    const float* cg2_Ws = (const float*)d_in[38];
    const float* cg2_Wd = (const float*)d_in[39];
    const float* cg2_as = (const float*)d_in[40];
    const float* cg2_ad = (const float*)d_in[41];
    const float* sa_W  = (const float*)d_in[42];
    const float* sa_b  = (const float*)d_in[43];
    const float* sa_v  = (const float*)d_in[44];
    const float* gate_W = (const float*)d_in[45];
    const float* gate_b = (const float*)d_in[46];
    const float* ww_W  = (const float*)d_in[47];
    const float* ww_b  = (const float*)d_in[48];
    float* out = (float*)d_out;

    char* p = (char*)d_ws;
    auto alloc = [&](size_t bytes) -> void* {
        void* r = (void*)p;
        p += (bytes + 255) & ~(size_t)255;
        return r;
    };
    int* g_off  = (int*)alloc((Nq + 1) * 4);
    int* bn_off = (int*)alloc((Nq + 1) * 4);
    int* bw_off = (int*)alloc((NEWSq + 1) * 4);
    int* g_src  = (int*)alloc(Eq * 4);
    int* bn_src = (int*)alloc(BEq * 4);
    int* bw_src = (int*)alloc(BEq * 4);
    int* cnt3   = (int*)alloc((2 * Nq + NEWSq) * 4);
    int* cur3   = (int*)alloc((2 * Nq + NEWSq) * 4);
    int* cg  = cnt3, *cbn = cnt3 + Nq, *cbw = cnt3 + 2 * Nq;
    int* curg = cur3, *curbn = cur3 + Nq, *curbw = cur3 + 2 * Nq;

    float* wscore  = (float*)alloc(WVOCq * 4);
    float* UTraw   = (float*)alloc((size_t)Bq * Hq * 128 * 4);
    float* UT3     = (float*)alloc((size_t)Bq * Hq * 128 * 4);
    float* news1   = (float*)alloc((size_t)NEWSq * 128 * 4);
    float* NC1     = (float*)alloc((size_t)NEWSq * 128 * 4);
    float* news2   = (float*)alloc((size_t)NEWSq * 128 * 4);
    float* NC2     = (float*)alloc((size_t)NEWSq * 128 * 4);
    float* newsS1  = (float*)alloc((size_t)NEWSq * 128 * 4);   // hs_news
    float* v0      = (float*)alloc((size_t)Nq * 128 * 4);
    float* v1      = (float*)alloc((size_t)Nq * 128 * 4);
    float* nc1     = (float*)alloc((size_t)Nq * 128 * 4);
    float* v2      = (float*)alloc((size_t)Nq * 128 * 4);
    float* nc2     = (float*)alloc((size_t)Nq * 128 * 4);
    float* nodeS1  = (float*)alloc((size_t)Nq * 128 * 4);      // hs_node / GAT h
    float* qb      = (float*)alloc((size_t)Bq * Hq * 128 * 4); // XM
    float* vb      = (float*)alloc((size_t)Bq * Hq * 128 * 4); // V
    float* es_node = (float*)alloc(Nq * 4);
    float* ed_node = (float*)alloc(Nq * 4);
    float* es_news = (float*)alloc(NEWSq * 4);
    float* gate    = (float*)alloc(Nq * 4);
    float* score_bh = (float*)alloc(Bq * Hq * 4);
    float* wdvec1  = (float*)alloc(128 * 4);
    float* wdvec2  = (float*)alloc(128 * 4);
    float* M1      = (float*)alloc(128 * 128 * 4);
    float* M2      = (float*)alloc(128 * 128 * 4);
    float* M3      = (float*)alloc(128 * 128 * 4);

    const int MH = Bq * Hq;          // 6400
    const int nbMH   = (MH + MMROWS - 1) / MMROWS;      // 200
    const int nbNode = (Nq + MMROWS - 1) / MMROWS;      // 320
    const int nbNews = (NEWSq + MMROWS - 1) / MMROWS;   // 220
    const int TOTE = Eq + 2 * BEq;
    const int BIG = 0x7fffffff;
    const int nCount = (TOTE + 255) / 256;              // 860
    const int nEmbed = (Nq * 32 + 255) / 256;           // 1280
    const int nWS    = (WVOCq + MMROWS - 1) / MMROWS;   // 1563
    const int nMprep = (3 * 16384) / 256;               // 192

    auto mkjob = [](const float* A, const float* W, float* C, const float* q0, const float* q1,
                    float* o0, float* o1, int M, int end, int amap) {
        MMJob j; j.A = A; j.W = W; j.C = C; j.q0 = q0; j.q1 = q1; j.o0 = o0; j.o1 = o1;
        j.M = M; j.blk_end = end; j.amap = amap; return j;
    };
    auto mkea = [](const int* off, const int* srcs, const float* es, const float* ed,
                   const float* edvec, const float* Hsrc, const float* Xdst,
                   float* Out, int nseg, int mode) {
        EASet s; s.off = off; s.srcs = srcs; s.es = es; s.ed = ed; s.edvec = edvec;
        s.Hsrc = Hsrc; s.Xdst = Xdst; s.Out = Out; s.nseg = nseg; s.mode = mode; return s;
    };
    MMJob jNone = mkjob(nullptr, nullptr, nullptr, nullptr, nullptr, nullptr, nullptr, 0, BIG, 0);

    MPrep mp;
    mp.wq0 = ue1_Wq; mp.wk0 = ue1_Wk; mp.m0 = M1;
    mp.wq1 = ue2_Wq; mp.wk1 = ue2_Wk; mp.m1 = M2;
    mp.wq2 = ue3_Wq; mp.wk2 = ue3_Wk; mp.m2 = M3;

    // L0: zero CSR counters
    hipMemsetAsync(cnt3, 0, (size_t)(2 * Nq + NEWSq) * 4, stream);
    // L1: count || embed || word-score || wdvec || Mprep
    k_misc1<<<nCount + nEmbed + nWS + 1 + nMprep, 256, 0, stream>>>(
        ei_dst, bi_node, bi_news, cg, cbn, cbw,
        nodes, ent_emb, v0,
        word_emb, te_W, te_b, te_v, wscore,
        cg1_Wd, cg1_ad, wdvec1, cg2_Wd, cg2_ad, wdvec2,
        mp, nCount, nEmbed, nWS);
    // L2: scan
    k_scan3<<<3, 1024, 0, stream>>>(cg, cbn, cbw, g_off, bn_off, bw_off, curg, curbn, curbw);
    // L3: scatter || title_pool
    k_misc2<<<nCount + (Bq * Sq) / 2, 256, 0, stream>>>(
        ei_src, ei_dst, bi_news, bi_node, curg, curbn, curbw, g_src, bn_src, bw_src,
        title_tok, wscore, word_emb,
        hist_seqs, hist_lens, pos_seq, pos_len, neg_seqs, neg_lens, UTraw, news1, nCount);

    // L4: XM1 || V1 || GAT1 matmul
    {
        MMJobs js;
        js.j[0] = mkjob(UTraw, M1,     qb, nullptr, nullptr, nullptr, nullptr, MH, nbMH, 0);
        js.j[1] = mkjob(UTraw, ue1_Wv, vb, nullptr, nullptr, nullptr, nullptr, MH, 2 * nbMH, 0);
        js.j[2] = mkjob(v0, g1_W, nodeS1, g1_as, g1_ad, es_node, ed_node, Nq, BIG, 0);
        js.j[3] = jNone;
        k_mm_jobs<<<2 * nbMH + nbNode, 256, 0, stream>>>(js);
    }
    // L5: attn1 (keys = UTraw)
    k_self_attn<<<Bq, 256, 0, stream>>>(qb, UTraw, vb, news1, Sq * 128, nullptr, 0,
                                        nullptr, nullptr, nullptr);
    // L6: cross1 news-Ws matmul || GAT1 edge-agg
    k_ea_mm<<<nbNews + (Nq + 3) / 4, 256, 0, stream>>>(
        mkjob(news1, cg1_Ws, newsS1, cg1_as, nullptr, es_news, nullptr, NEWSq, BIG, 0), nbNews,
        mkea(g_off, g_src, es_node, ed_node, nullptr, nodeS1, nullptr, v1, Nq, 0));
    // L7: cross1 node-Ws matmul
    {
        MMJobs js;
        js.j[0] = mkjob(v1, cg1_Ws, nodeS1, cg1_as, nullptr, es_node, nullptr, Nq, BIG, 0);
        js.j[1] = js.j[2] = js.j[3] = jNone;
        k_mm_jobs<<<nbNode, 256, 0, stream>>>(js);
    }
    // L8: both cross1 edge_aggs (16-lane teams, ed inline via wdvec1)
    k_ea16<<<(Nq + NEWSq + 15) / 16, 256, 0, stream>>>(
        mkea(bn_off, bn_src, es_news, nullptr, wdvec1, newsS1, v1, nc1, Nq, 1),
        mkea(bw_off, bw_src, es_node, nullptr, wdvec1, nodeS1, news1, NC1, NEWSq, 1),
        nullptr, nullptr, nullptr);

    // L9: XM2 || V2 (NC1 gather) || GAT2 matmul
    {
        MMJobs js;
        js.j[0] = mkjob(NC1, M2,     qb, nullptr, nullptr, nullptr, nullptr, MH, nbMH, 1);
        js.j[1] = mkjob(NC1, ue2_Wv, vb, nullptr, nullptr, nullptr, nullptr, MH, 2 * nbMH, 1);
        js.j[2] = mkjob(nc1, g2_W, nodeS1, g2_as, g2_ad, es_node, ed_node, Nq, BIG, 0);
        js.j[3] = jNone;
        k_mm_jobs<<<2 * nbMH + nbNode, 256, 0, stream>>>(js);
    }
    // L10: attn2 (keys = NC1 gathered; + tail copy)
    k_self_attn<<<Bq, 256, 0, stream>>>(qb, NC1, vb, news2, Sq * 128, NC1, 1,
                                        nullptr, nullptr, nullptr);
    // L11: cross2 news-Ws matmul || GAT2 edge-agg
    k_ea_mm<<<nbNews + (Nq + 3) / 4, 256, 0, stream>>>(
        mkjob(news2, cg2_Ws, newsS1, cg2_as, nullptr, es_news, nullptr, NEWSq, BIG, 0), nbNews,
        mkea(g_off, g_src, es_node, ed_node, nullptr, nodeS1, nullptr, v2, Nq, 0));
    // L12: cross2 node-Ws matmul
    {
        MMJobs js;
        js.j[0] = mkjob(v2, cg2_Ws, nodeS1, cg2_as, nullptr, es_node, nullptr, Nq, BIG, 0);
        js.j[1] = js.j[2] = js.j[3] = jNone;
        k_mm_jobs<<<nbNode, 256, 0, stream>>>(js);
    }
    // L13: both cross2 edge_aggs (16-lane teams; + fused gate)
    k_ea16<<<(Nq + NEWSq + 15) / 16, 256, 0, stream>>>(
        mkea(bn_off, bn_src, es_news, nullptr, wdvec2, newsS1, v2, nc2, Nq, 1),
        mkea(bw_off, bw_src, es_node, nullptr, wdvec2, nodeS1, news2, NC2, NEWSq, 1),
        gate_W, gate_b, gate);

    // L14: XM3 || V3 (NC2 gather)
    {
        MMJobs js;
        js.j[0] = mkjob(NC2, M3,     qb, nullptr, nullptr, nullptr, nullptr, MH, nbMH, 1);
        js.j[1] = mkjob(NC2, ue3_Wv, vb, nullptr, nullptr, nullptr, nullptr, MH, 2 * nbMH, 1);
        js.j[2] = js.j[3] = jNone;
        k_mm_jobs<<<2 * nbMH, 256, 0, stream>>>(js);
    }
    // L15: attn3 (keys = NC2 gathered) + fused sa tanh-dot score
    k_self_attn<<<Bq, 256, 0, stream>>>(qb, NC2, vb, UT3, Hq * 128, nullptr, 1,
                                        sa_b, sa_v, score_bh);
    // L16: fused final
    k_final_fused<<<Bq * NEG1q, 128, 0, stream>>>(UT3, score_bh, nc2, gate,
        hist_mask, pos_mask, neg_masks, NC2, ww_W, ww_b, out);
}